// Round 11
// baseline (215.901 us; speedup 1.0000x reference)
//
#include <hip/hip_runtime.h>
#include <hip/hip_bf16.h>
#include <math.h>

typedef unsigned short u16;
using short8 = __attribute__((ext_vector_type(8))) short;
using f32x4  = __attribute__((ext_vector_type(4))) float;

#define BK 32

// ---------- helpers ----------

__device__ __forceinline__ u16 f2bf(float f) {
  union { float f; unsigned u; } v; v.f = f;
  unsigned r = v.u + 0x7FFFu + ((v.u >> 16) & 1u);   // RNE
  return (u16)(r >> 16);
}

__device__ __forceinline__ float fexp(float x) { return __expf(x); }

__device__ __forceinline__ void gld16(const void* g, void* l) {
  __builtin_amdgcn_global_load_lds(
      (const __attribute__((address_space(1))) void*)g,
      (__attribute__((address_space(3))) void*)l,
      16, 0, 0);
}

// ---------- 4-wave GEMM core (R0-proven): 16x16x32 MFMA, BK=64 ----------
// 128x128 C tile of A[*,lda] @ B[*,ldb]^T, row-major K-contiguous bf16.
// Simple 2-barrier drain loop; relies on multi-block residency for overlap.
// K-layout-agnostic: any permutation of the K axis applied identically to
// A and B rows leaves C invariant (verified R6).
// Staging algebra: LDS row r, physical chunk p holds logical chunk
// p ^ ((r>>1)&3); read side kro = (lq ^ ((ln>>1)&3))*8 matches.

__device__ __forceinline__ void gemm_core64(const u16* __restrict__ Ag,
                                            const u16* __restrict__ Bg,
                                            int K, int lda, int ldb,
                                            u16* As, u16* Bs,
                                            f32x4 acc[4][4], int w, int l) {
  const int wm = (w & 1) << 6, wn = (w >> 1) << 6;
  const int ln = l & 15, lq = l >> 4;
  const int sr0 = w * 16 + (l >> 2);
  const int sr1 = 64 + sr0;
  const int skp = (l & 3) * 8;                       // physical LDS chunk
  const int skg = ((l & 3) ^ ((l >> 3) & 3)) * 8;    // logical/global chunk
  const int kro = (lq ^ ((ln >> 1) & 3)) * 8;        // read-side phys chunk

#pragma unroll
  for (int mt = 0; mt < 4; mt++)
#pragma unroll
    for (int nt = 0; nt < 4; nt++) acc[mt][nt] = (f32x4)0.0f;

  for (int k0 = 0; k0 < K; k0 += 64) {
    __syncthreads();
    gld16(Ag + (size_t)sr0 * lda + k0 + skg, As + sr0 * BK + skp);
    gld16(Ag + (size_t)sr1 * lda + k0 + skg, As + sr1 * BK + skp);
    gld16(Ag + (size_t)sr0 * lda + k0 + 32 + skg, As + 4096 + sr0 * BK + skp);
    gld16(Ag + (size_t)sr1 * lda + k0 + 32 + skg, As + 4096 + sr1 * BK + skp);
    gld16(Bg + (size_t)sr0 * ldb + k0 + skg, Bs + sr0 * BK + skp);
    gld16(Bg + (size_t)sr1 * ldb + k0 + skg, Bs + sr1 * BK + skp);
    gld16(Bg + (size_t)sr0 * ldb + k0 + 32 + skg, Bs + 4096 + sr0 * BK + skp);
    gld16(Bg + (size_t)sr1 * ldb + k0 + 32 + skg, Bs + 4096 + sr1 * BK + skp);
    __syncthreads();
#pragma unroll
    for (int h = 0; h < 2; h++) {
      const u16* Ah = As + h * 4096;
      const u16* Bh = Bs + h * 4096;
      short8 af[4], bf[4];
#pragma unroll
      for (int mt = 0; mt < 4; mt++)
        af[mt] = *(const short8*)(Ah + (wm + mt * 16 + ln) * BK + kro);
#pragma unroll
      for (int nt = 0; nt < 4; nt++)
        bf[nt] = *(const short8*)(Bh + (wn + nt * 16 + ln) * BK + kro);
#pragma unroll
      for (int mt = 0; mt < 4; mt++)
#pragma unroll
        for (int nt = 0; nt < 4; nt++)
          acc[mt][nt] = __builtin_amdgcn_mfma_f32_16x16x32_bf16(
              af[mt], bf[nt], acc[mt][nt], 0, 0, 0);
    }
  }
}

// ---------- projection: fully fused (x->bf16, W->bf16^T, bias, lsum) ----------
// 3-kernel pipeline: k_conv eliminated. Per block:
//  - lsum zeroing (bnq==3 stripe; proj completes before k_qk -> safe)
//  - A slab: fp32 x nt-loads + f2bf + LDS (R10-proven; nt keeps x from
//    evicting qb/kb lines that k_qk re-reads)
//  - B tiles: fp32 W rows read COALESCED (f32x4 along c) + f2bf + scattered
//    ds_write_u16 into the swizzled slot Bs[c*32 + ((kc^((c>>1)&3))*8) + ko]
//    -- bit-identical to the old Wt gld16 path; W (1.5MB) stays L2-hot.
//  - bias read direct from bq/bk/bv (bcat eliminated).
// vtb t-axis PERMUTED within each 64-group (matches k_qk's P columns);
// scratch writes regrouped across mt into ONE ushort4 per (nt,r) (fixes the
// R10 scalar-u16 scatter regression).

__global__ __launch_bounds__(256) void k_proj(
    const float* __restrict__ x,
    const float* __restrict__ Wq, const float* __restrict__ Wk,
    const float* __restrict__ Wv, const float* __restrict__ bq,
    const float* __restrict__ bk, const float* __restrict__ bv,
    u16* __restrict__ qb, u16* __restrict__ kb, u16* __restrict__ vtb,
    float* __restrict__ lsum) {
  __shared__ __align__(16) u16 As8[8 * 4096];  // 64 KB: 8 windows x [128][32]
  __shared__ __align__(16) u16 Bs[2 * 4096];   // 16 KB: 2 windows
  const int bm = blockIdx.y * 128;
  const int bnq = blockIdx.x;                  // 0..3: 128-col quarter of 512
  const int tid = threadIdx.x, w = tid >> 6, l = tid & 63;
  const int wm = (w & 1) << 6, wn = (w >> 1) << 6;
  const int ln = l & 15, lq = l >> 4;
  const int sr0 = w * 16 + (l >> 2);
  const int sr1 = 64 + sr0;
  const int skp = (l & 3) * 8;
  const int skg = ((l & 3) ^ ((l >> 3) & 3)) * 8;
  const int kro = (lq ^ ((ln >> 1) & 3)) * 8;

  // lsum zeroing (64 of the 128 bnq==3 blocks cover 16384 floats)
  if (bnq == 3) {
    int i = blockIdx.y * 256 + tid;
    if (i < 16384) lsum[i] = 0.0f;
  }

  // stage all 8 A windows once: fp32 nt-load + convert + LDS write
#pragma unroll
  for (int kw = 0; kw < 8; kw++) {
    const f32x4* s0 = (const f32x4*)(x + (size_t)(bm + sr0) * 256 + kw * 32 + skg);
    const f32x4* s1 = (const f32x4*)(x + (size_t)(bm + sr1) * 256 + kw * 32 + skg);
    f32x4 a0 = __builtin_nontemporal_load(s0);
    f32x4 a1 = __builtin_nontemporal_load(s0 + 1);
    f32x4 b0 = __builtin_nontemporal_load(s1);
    f32x4 b1 = __builtin_nontemporal_load(s1 + 1);
    short8 v0, v1;
#pragma unroll
    for (int j = 0; j < 4; j++) {
      ((u16*)&v0)[j]     = f2bf(a0[j]);
      ((u16*)&v0)[4 + j] = f2bf(a1[j]);
      ((u16*)&v1)[j]     = f2bf(b0[j]);
      ((u16*)&v1)[4 + j] = f2bf(b1[j]);
    }
    *(short8*)(As8 + kw * 4096 + sr0 * BK + skp) = v0;
    *(short8*)(As8 + kw * 4096 + sr1 * BK + skp) = v1;
  }

  const int b = bm >> 11, t0 = bm & 2047;
  const int cb = bnq * 128;

  // B-staging thread map: er = e-offset in 64-window, c spans 128 cols
  const int er = tid >> 2;                     // 0..63
  const int cq = (tid & 3) * 32;               // c base (8 f32x4 along c)
  const int bh = er >> 5;                      // which 32-wide half
  const int kc = (er & 31) >> 3, ko = er & 7;  // chunk / offset within chunk

  for (int p = 0; p < 3; p++) {
    const float* Wp = (p == 0) ? Wq : (p == 1) ? Wk : Wv;
    f32x4 acc[4][4];
#pragma unroll
    for (int mt = 0; mt < 4; mt++)
#pragma unroll
      for (int nt = 0; nt < 4; nt++) acc[mt][nt] = (f32x4)0.0f;

#pragma unroll
    for (int it2 = 0; it2 < 4; it2++) {
      __syncthreads();
      // fused W -> bf16 transposed staging (replaces Wt gld16)
      {
        const float* wrow = Wp + (size_t)(it2 * 64 + er) * 512 + cb + cq;
        u16* dstb = Bs + bh * 4096;
#pragma unroll
        for (int j = 0; j < 8; j++) {
          f32x4 wv = *(const f32x4*)(wrow + j * 4);
#pragma unroll
          for (int i = 0; i < 4; i++) {
            int c = cq + j * 4 + i;
            dstb[c * 32 + ((kc ^ ((c >> 1) & 3)) * 8) + ko] = f2bf(wv[i]);
          }
        }
      }
      __syncthreads();
#pragma unroll
      for (int h = 0; h < 2; h++) {
        const u16* Aw = As8 + (it2 * 2 + h) * 4096;
        const u16* Bh = Bs + h * 4096;
        short8 af[4], bf[4];
#pragma unroll
        for (int mt = 0; mt < 4; mt++)
          af[mt] = *(const short8*)(Aw + (wm + mt * 16 + ln) * BK + kro);
#pragma unroll
        for (int nt = 0; nt < 4; nt++)
          bf[nt] = *(const short8*)(Bh + (wn + nt * 16 + ln) * BK + kro);
#pragma unroll
        for (int mt = 0; mt < 4; mt++)
#pragma unroll
          for (int nt = 0; nt < 4; nt++)
            acc[mt][nt] = __builtin_amdgcn_mfma_f32_16x16x32_bf16(
                af[mt], bf[nt], acc[mt][nt], 0, 0, 0);
      }
    }

    if (p < 2) {
      // PERMUTED channel layout within each 64-col group (R6-verified):
      // memory position m = ln*4 + nt holds logical channel nt*16 + ln.
      // Applied identically to qb AND kb -> QK^T invariant.
      u16* dst = p ? kb : qb;
      const float* bias = p ? bk : bq;
#pragma unroll
      for (int mt = 0; mt < 4; mt++)
#pragma unroll
        for (int r = 0; r < 4; r++) {
          int row = bm + wm + mt * 16 + lq * 4 + r;
          ushort4 o;
#pragma unroll
          for (int nt = 0; nt < 4; nt++) {
            int col = wn + nt * 16 + ln;           // logical col (bias idx)
            float v = acc[mt][nt][r] + bias[cb + col];
            float ov = (p == 0) ? __builtin_amdgcn_rcpf(1.0f + fexp(-v)) : v;
            ((u16*)&o)[nt] = f2bf(ov);
          }
          *(ushort4*)&dst[(size_t)row * 512 + cb + wn + ln * 4] = o;
        }
    } else {
      // v path: transpose to vtb[b][col][t], t-axis permuted within each
      // 64-group (logical local-t mt*16+lq*4+r at position lq*16+r*4+mt).
      // Regrouped across mt -> one ushort4 LDS store per (nt,r).
      u16* tr = As8;                            // reuse dead A slab
#pragma unroll
      for (int h = 0; h < 2; h++) {
        __syncthreads();
        if ((w & 1) == h) {
#pragma unroll
          for (int nt = 0; nt < 4; nt++) {
            int c = wn + nt * 16 + ln;
            float bias = bv[cb + c];
#pragma unroll
            for (int r = 0; r < 4; r++) {
              ushort4 o;
#pragma unroll
              for (int mm = 0; mm < 4; mm++)
                ((u16*)&o)[mm] = f2bf(acc[mm][nt][r] + bias);
              *(ushort4*)&tr[c * 68 + lq * 16 + r * 4] = o;
            }
          }
        }
        __syncthreads();
        int c2 = tid >> 1, half = tid & 1;
        size_t dbase = ((size_t)b * 512 + cb + c2) * 2048 + t0 + h * 64 + half * 32;
#pragma unroll
        for (int j = 0; j < 4; j++) {
          ushort4 a0 = *(const ushort4*)&tr[c2 * 68 + half * 32 + j * 8];
          ushort4 a1 = *(const ushort4*)&tr[c2 * 68 + half * 32 + j * 8 + 4];
          *(ushort4*)&vtb[dbase + j * 8] = a0;
          *(ushort4*)&vtb[dbase + j * 8 + 4] = a1;
        }
      }
    }
  }
}

// ---------- QK^T + elu + exp -> P (bf16, permuted cols), row sums ----------

__global__ __launch_bounds__(256, 4) void k_qk(const u16* __restrict__ qb,
                                               const u16* __restrict__ kb,
                                               u16* __restrict__ P,
                                               float* __restrict__ lsum) {
  __shared__ __align__(16) u16 As[2 * 4096];   // 16 KB (BK=64, 2 windows)
  __shared__ __align__(16) u16 Bs[2 * 4096];   // 16 KB
  // bid%8 = batch = XCD round-robin: each XCD's L2 keeps its batch's q+k (4MB)
  const int bid = blockIdx.x;
  const int b = bid & 7, t = bid >> 3;
  const int bm = (t >> 4) * 128, bn = (t & 15) * 128;
  const size_t ob = (size_t)b * 2048 * 512;
  const int tid = threadIdx.x, w = tid >> 6, l = tid & 63;
  f32x4 acc[4][4];
  gemm_core64(qb + ob + (size_t)bm * 512, kb + ob + (size_t)bn * 512,
              512, 512, 512, As, Bs, acc, w, l);

  const int wm = (w & 1) << 6, wn = (w >> 1) << 6;
  const int ln = l & 15, lq = l >> 4;
  const float scale = 0.0625f;  // 1/sqrt(256)
  // P columns stored PERMUTED within each aligned 64-group: memory position
  // m = ln*4 + nt holds logical kv-col nt*16 + ln. vtb's t-axis uses the
  // same permutation -> P@V invariant. One ushort4 store per (mt,r).
#pragma unroll
  for (int mt = 0; mt < 4; mt++)
#pragma unroll
    for (int r = 0; r < 4; r++) {
      int row = bm + wm + mt * 16 + lq * 4 + r;
      float s = 0.0f;
      ushort4 o;
#pragma unroll
      for (int nt = 0; nt < 4; nt++) {
        float v = acc[mt][nt][r] * scale;
        float e = (v > 0.0f) ? v : (fexp(v) - 1.0f);   // elu (hw exp)
        float p = fexp(e);    // unnormalized softmax (elu >= -1, no max sub)
        ((u16*)&o)[nt] = f2bf(p);
        s += p;
      }
      *(ushort4*)&P[((size_t)b * 2048 + row) * 2048 + bn + wn + ln * 4] = o;
#pragma unroll
      for (int o2 = 1; o2 < 16; o2 <<= 1) s += __shfl_xor(s, o2);
      if (ln == 0) atomicAdd(&lsum[b * 2048 + row], s);
    }
}

// ---------- P @ V, divide by row sum, fp32 out; XCD-swizzled ----------

__global__ __launch_bounds__(256, 4) void k_pv(const u16* __restrict__ P,
                                               const u16* __restrict__ vtb,
                                               const float* __restrict__ lsum,
                                               float* __restrict__ out) {
  __shared__ __align__(16) u16 As[2 * 4096];
  __shared__ __align__(16) u16 Bs[2 * 4096];
  // bid%8 = batch = XCD: vtb slab (2MB) L2-resident; bn fastest -> P-slab reuse
  const int bid = blockIdx.x;
  const int b = bid & 7, t = bid >> 3;
  const int bm = (t >> 2) * 128, bn = (t & 3) * 128;
  const int tid = threadIdx.x, w = tid >> 6, l = tid & 63;
  f32x4 acc[4][4];
  gemm_core64(P  + (size_t)b * 2048 * 2048 + (size_t)bm * 2048,
              vtb + (size_t)b * 512 * 2048 + (size_t)bn * 2048,
              2048, 2048, 2048, As, Bs, acc, w, l);

  const int wm = (w & 1) << 6, wn = (w >> 1) << 6;
  const int ln = l & 15, lq = l >> 4;
#pragma unroll
  for (int mt = 0; mt < 4; mt++)
#pragma unroll
    for (int r = 0; r < 4; r++) {
      int row = bm + wm + mt * 16 + lq * 4 + r;
      float inv = 1.0f / lsum[b * 2048 + row];
#pragma unroll
      for (int nt = 0; nt < 4; nt++) {
        int col = bn + wn + nt * 16 + ln;
        __builtin_nontemporal_store(acc[mt][nt][r] * inv,
            &out[((size_t)b * 2048 + row) * 512 + col]);
      }
    }
}

// ---------- launch ----------

extern "C" void kernel_launch(void* const* d_in, const int* in_sizes, int n_in,
                              void* d_out, int out_size, void* d_ws, size_t ws_size,
                              hipStream_t stream) {
  const float* x  = (const float*)d_in[0];
  const float* Wq = (const float*)d_in[1];
  const float* bq = (const float*)d_in[2];
  const float* Wk = (const float*)d_in[3];
  const float* bk = (const float*)d_in[4];
  const float* Wv = (const float*)d_in[5];
  const float* bv = (const float*)d_in[6];
  float* out = (float*)d_out;
  char* ws = (char*)d_ws;

  u16*  qb   = (u16*)(ws + 0);            // 16,777,216
  u16*  kb   = (u16*)(ws + 16777216);     // 16,777,216
  u16*  vtb  = (u16*)(ws + 33554432);     // 16,777,216
  float* lsum = (float*)(ws + 50331648);  //     65,536
  u16*  P    = (u16*)(ws + 50397184);     // 67,108,864 (ends 117,506,048)

  k_proj<<<dim3(4, 128, 1), 256, 0, stream>>>(x, Wq, Wk, Wv, bq, bk, bv,
                                              qb, kb, vtb, lsum);
  k_qk<<<2048, 256, 0, stream>>>(qb, kb, P, lsum);
  k_pv<<<512, 256, 0, stream>>>(P, vtb, lsum, out);
}

// Round 12
// 206.753 us; speedup vs baseline: 1.0442x; 1.0442x over previous
//
#include <hip/hip_runtime.h>
#include <hip/hip_bf16.h>
#include <math.h>

typedef unsigned short u16;
using short8 = __attribute__((ext_vector_type(8))) short;
using f32x4  = __attribute__((ext_vector_type(4))) float;

#define BK 32

// ---------- helpers ----------

__device__ __forceinline__ u16 f2bf(float f) {
  union { float f; unsigned u; } v; v.f = f;
  unsigned r = v.u + 0x7FFFu + ((v.u >> 16) & 1u);   // RNE
  return (u16)(r >> 16);
}

__device__ __forceinline__ float fexp(float x) { return __expf(x); }

__device__ __forceinline__ void gld16(const void* g, void* l) {
  __builtin_amdgcn_global_load_lds(
      (const __attribute__((address_space(1))) void*)g,
      (__attribute__((address_space(3))) void*)l,
      16, 0, 0);
}

// ---------- 4-wave GEMM core (R0-proven): 16x16x32 MFMA, BK=64 ----------
// 128x128 C tile of A[*,lda] @ B[*,ldb]^T, row-major K-contiguous bf16.
// Simple 2-barrier drain loop; relies on multi-block residency for overlap.
// K-layout-agnostic (verified R6). Staging algebra: LDS row r, physical
// chunk p holds logical chunk p ^ ((r>>1)&3); read kro matches.

__device__ __forceinline__ void gemm_core64(const u16* __restrict__ Ag,
                                            const u16* __restrict__ Bg,
                                            int K, int lda, int ldb,
                                            u16* As, u16* Bs,
                                            f32x4 acc[4][4], int w, int l) {
  const int wm = (w & 1) << 6, wn = (w >> 1) << 6;
  const int ln = l & 15, lq = l >> 4;
  const int sr0 = w * 16 + (l >> 2);
  const int sr1 = 64 + sr0;
  const int skp = (l & 3) * 8;                       // physical LDS chunk
  const int skg = ((l & 3) ^ ((l >> 3) & 3)) * 8;    // logical/global chunk
  const int kro = (lq ^ ((ln >> 1) & 3)) * 8;        // read-side phys chunk

#pragma unroll
  for (int mt = 0; mt < 4; mt++)
#pragma unroll
    for (int nt = 0; nt < 4; nt++) acc[mt][nt] = (f32x4)0.0f;

  for (int k0 = 0; k0 < K; k0 += 64) {
    __syncthreads();
    gld16(Ag + (size_t)sr0 * lda + k0 + skg, As + sr0 * BK + skp);
    gld16(Ag + (size_t)sr1 * lda + k0 + skg, As + sr1 * BK + skp);
    gld16(Ag + (size_t)sr0 * lda + k0 + 32 + skg, As + 4096 + sr0 * BK + skp);
    gld16(Ag + (size_t)sr1 * lda + k0 + 32 + skg, As + 4096 + sr1 * BK + skp);
    gld16(Bg + (size_t)sr0 * ldb + k0 + skg, Bs + sr0 * BK + skp);
    gld16(Bg + (size_t)sr1 * ldb + k0 + skg, Bs + sr1 * BK + skp);
    gld16(Bg + (size_t)sr0 * ldb + k0 + 32 + skg, Bs + 4096 + sr0 * BK + skp);
    gld16(Bg + (size_t)sr1 * ldb + k0 + 32 + skg, Bs + 4096 + sr1 * BK + skp);
    __syncthreads();
#pragma unroll
    for (int h = 0; h < 2; h++) {
      const u16* Ah = As + h * 4096;
      const u16* Bh = Bs + h * 4096;
      short8 af[4], bf[4];
#pragma unroll
      for (int mt = 0; mt < 4; mt++)
        af[mt] = *(const short8*)(Ah + (wm + mt * 16 + ln) * BK + kro);
#pragma unroll
      for (int nt = 0; nt < 4; nt++)
        bf[nt] = *(const short8*)(Bh + (wn + nt * 16 + ln) * BK + kro);
#pragma unroll
      for (int mt = 0; mt < 4; mt++)
#pragma unroll
        for (int nt = 0; nt < 4; nt++)
          acc[mt][nt] = __builtin_amdgcn_mfma_f32_16x16x32_bf16(
              af[mt], bf[nt], acc[mt][nt], 0, 0, 0);
    }
  }
}

// ---------- projection: fully fused (x->bf16, W->bf16^T, bias, lsum) ----------
// R11 structure with CONFLICT-FREE W staging: R11's scattered ds_write_u16
// (64B stride -> 2-bank alternation, 4.7M conflicts) is replaced by a
// register transpose: thread owns (column cw, e-half khi), builds 4 logical
// chunks as short8 via 8 stride-2KB scalar W reads each (coalesced across
// lanes: 64 consecutive cw = 256B segments; W quarter L2-hot across 128
// blocks), then ONE ds_write_b128 per chunk into the swizzled slot --
// identical bank pattern to the A-staging writes (measured conflict-free).

__global__ __launch_bounds__(256) void k_proj(
    const float* __restrict__ x,
    const float* __restrict__ Wq, const float* __restrict__ Wk,
    const float* __restrict__ Wv, const float* __restrict__ bq,
    const float* __restrict__ bk, const float* __restrict__ bv,
    u16* __restrict__ qb, u16* __restrict__ kb, u16* __restrict__ vtb,
    float* __restrict__ lsum) {
  __shared__ __align__(16) u16 As8[8 * 4096];  // 64 KB: 8 windows x [128][32]
  __shared__ __align__(16) u16 Bs[2 * 4096];   // 16 KB: 2 windows
  const int bm = blockIdx.y * 128;
  const int bnq = blockIdx.x;                  // 0..3: 128-col quarter of 512
  const int tid = threadIdx.x, w = tid >> 6, l = tid & 63;
  const int wm = (w & 1) << 6, wn = (w >> 1) << 6;
  const int ln = l & 15, lq = l >> 4;
  const int sr0 = w * 16 + (l >> 2);
  const int sr1 = 64 + sr0;
  const int skp = (l & 3) * 8;
  const int skg = ((l & 3) ^ ((l >> 3) & 3)) * 8;
  const int kro = (lq ^ ((ln >> 1) & 3)) * 8;

  // lsum zeroing (64 of the 128 bnq==3 blocks cover 16384 floats)
  if (bnq == 3) {
    int i = blockIdx.y * 256 + tid;
    if (i < 16384) lsum[i] = 0.0f;
  }

  // stage all 8 A windows once: fp32 nt-load + convert + LDS write
#pragma unroll
  for (int kw = 0; kw < 8; kw++) {
    const f32x4* s0 = (const f32x4*)(x + (size_t)(bm + sr0) * 256 + kw * 32 + skg);
    const f32x4* s1 = (const f32x4*)(x + (size_t)(bm + sr1) * 256 + kw * 32 + skg);
    f32x4 a0 = __builtin_nontemporal_load(s0);
    f32x4 a1 = __builtin_nontemporal_load(s0 + 1);
    f32x4 b0 = __builtin_nontemporal_load(s1);
    f32x4 b1 = __builtin_nontemporal_load(s1 + 1);
    short8 v0, v1;
#pragma unroll
    for (int j = 0; j < 4; j++) {
      ((u16*)&v0)[j]     = f2bf(a0[j]);
      ((u16*)&v0)[4 + j] = f2bf(a1[j]);
      ((u16*)&v1)[j]     = f2bf(b0[j]);
      ((u16*)&v1)[4 + j] = f2bf(b1[j]);
    }
    *(short8*)(As8 + kw * 4096 + sr0 * BK + skp) = v0;
    *(short8*)(As8 + kw * 4096 + sr1 * BK + skp) = v1;
  }

  const int b = bm >> 11, t0 = bm & 2047;
  const int cb = bnq * 128;

  // W-staging thread map: cw = column (0..127), khi = e-half (0/1)
  const int cw = tid & 127;
  const int khi = tid >> 7;
  const int csz = (cw >> 1) & 3;               // column's chunk swizzle

  for (int p = 0; p < 3; p++) {
    const float* Wp = (p == 0) ? Wq : (p == 1) ? Wk : Wv;
    f32x4 acc[4][4];
#pragma unroll
    for (int mt = 0; mt < 4; mt++)
#pragma unroll
      for (int nt = 0; nt < 4; nt++) acc[mt][nt] = (f32x4)0.0f;

#pragma unroll
    for (int it2 = 0; it2 < 4; it2++) {
      __syncthreads();
      // fused W -> bf16 transposed staging (register transpose, b128 writes)
      {
        const float* wbase = Wp + (size_t)(it2 * 64 + khi * 32) * 512 + cb + cw;
        u16* dstb = Bs + khi * 4096 + cw * 32;
#pragma unroll
        for (int j = 0; j < 4; j++) {          // logical chunk j of this half
          short8 o;
#pragma unroll
          for (int jj = 0; jj < 8; jj++)
            ((u16*)&o)[jj] = f2bf(wbase[(size_t)(j * 8 + jj) * 512]);
          *(short8*)(dstb + ((j ^ csz) * 8)) = o;
        }
      }
      __syncthreads();
#pragma unroll
      for (int h = 0; h < 2; h++) {
        const u16* Aw = As8 + (it2 * 2 + h) * 4096;
        const u16* Bh = Bs + h * 4096;
        short8 af[4], bf[4];
#pragma unroll
        for (int mt = 0; mt < 4; mt++)
          af[mt] = *(const short8*)(Aw + (wm + mt * 16 + ln) * BK + kro);
#pragma unroll
        for (int nt = 0; nt < 4; nt++)
          bf[nt] = *(const short8*)(Bh + (wn + nt * 16 + ln) * BK + kro);
#pragma unroll
        for (int mt = 0; mt < 4; mt++)
#pragma unroll
          for (int nt = 0; nt < 4; nt++)
            acc[mt][nt] = __builtin_amdgcn_mfma_f32_16x16x32_bf16(
                af[mt], bf[nt], acc[mt][nt], 0, 0, 0);
      }
    }

    if (p < 2) {
      // PERMUTED channel layout within each 64-col group (R6-verified):
      // memory position m = ln*4 + nt holds logical channel nt*16 + ln.
      // Applied identically to qb AND kb -> QK^T invariant.
      u16* dst = p ? kb : qb;
      const float* bias = p ? bk : bq;
#pragma unroll
      for (int mt = 0; mt < 4; mt++)
#pragma unroll
        for (int r = 0; r < 4; r++) {
          int row = bm + wm + mt * 16 + lq * 4 + r;
          ushort4 o;
#pragma unroll
          for (int nt = 0; nt < 4; nt++) {
            int col = wn + nt * 16 + ln;           // logical col (bias idx)
            float v = acc[mt][nt][r] + bias[cb + col];
            float ov = (p == 0) ? __builtin_amdgcn_rcpf(1.0f + fexp(-v)) : v;
            ((u16*)&o)[nt] = f2bf(ov);
          }
          *(ushort4*)&dst[(size_t)row * 512 + cb + wn + ln * 4] = o;
        }
    } else {
      // v path: transpose to vtb[b][col][t], t-axis permuted within each
      // 64-group (logical local-t mt*16+lq*4+r at position lq*16+r*4+mt).
      // Regrouped across mt -> one ushort4 LDS store per (nt,r).
      u16* tr = As8;                            // reuse dead A slab
#pragma unroll
      for (int h = 0; h < 2; h++) {
        __syncthreads();
        if ((w & 1) == h) {
#pragma unroll
          for (int nt = 0; nt < 4; nt++) {
            int c = wn + nt * 16 + ln;
            float bias = bv[cb + c];
#pragma unroll
            for (int r = 0; r < 4; r++) {
              ushort4 o;
#pragma unroll
              for (int mm = 0; mm < 4; mm++)
                ((u16*)&o)[mm] = f2bf(acc[mm][nt][r] + bias);
              *(ushort4*)&tr[c * 68 + lq * 16 + r * 4] = o;
            }
          }
        }
        __syncthreads();
        int c2 = tid >> 1, half = tid & 1;
        size_t dbase = ((size_t)b * 512 + cb + c2) * 2048 + t0 + h * 64 + half * 32;
#pragma unroll
        for (int j = 0; j < 4; j++) {
          ushort4 a0 = *(const ushort4*)&tr[c2 * 68 + half * 32 + j * 8];
          ushort4 a1 = *(const ushort4*)&tr[c2 * 68 + half * 32 + j * 8 + 4];
          *(ushort4*)&vtb[dbase + j * 8] = a0;
          *(ushort4*)&vtb[dbase + j * 8 + 4] = a1;
        }
      }
    }
  }
}

// ---------- QK^T + elu + exp -> P (bf16, permuted cols), row sums ----------

__global__ __launch_bounds__(256, 4) void k_qk(const u16* __restrict__ qb,
                                               const u16* __restrict__ kb,
                                               u16* __restrict__ P,
                                               float* __restrict__ lsum) {
  __shared__ __align__(16) u16 As[2 * 4096];   // 16 KB (BK=64, 2 windows)
  __shared__ __align__(16) u16 Bs[2 * 4096];   // 16 KB
  // bid%8 = batch = XCD round-robin: each XCD's L2 keeps its batch's q+k (4MB)
  const int bid = blockIdx.x;
  const int b = bid & 7, t = bid >> 3;
  const int bm = (t >> 4) * 128, bn = (t & 15) * 128;
  const size_t ob = (size_t)b * 2048 * 512;
  const int tid = threadIdx.x, w = tid >> 6, l = tid & 63;
  f32x4 acc[4][4];
  gemm_core64(qb + ob + (size_t)bm * 512, kb + ob + (size_t)bn * 512,
              512, 512, 512, As, Bs, acc, w, l);

  const int wm = (w & 1) << 6, wn = (w >> 1) << 6;
  const int ln = l & 15, lq = l >> 4;
  const float scale = 0.0625f;  // 1/sqrt(256)
  // P columns stored PERMUTED within each aligned 64-group: memory position
  // m = ln*4 + nt holds logical kv-col nt*16 + ln. vtb's t-axis uses the
  // same permutation -> P@V invariant. One ushort4 store per (mt,r).
#pragma unroll
  for (int mt = 0; mt < 4; mt++)
#pragma unroll
    for (int r = 0; r < 4; r++) {
      int row = bm + wm + mt * 16 + lq * 4 + r;
      float s = 0.0f;
      ushort4 o;
#pragma unroll
      for (int nt = 0; nt < 4; nt++) {
        float v = acc[mt][nt][r] * scale;
        float e = (v > 0.0f) ? v : (fexp(v) - 1.0f);   // elu (hw exp)
        float p = fexp(e);    // unnormalized softmax (elu >= -1, no max sub)
        ((u16*)&o)[nt] = f2bf(p);
        s += p;
      }
      *(ushort4*)&P[((size_t)b * 2048 + row) * 2048 + bn + wn + ln * 4] = o;
#pragma unroll
      for (int o2 = 1; o2 < 16; o2 <<= 1) s += __shfl_xor(s, o2);
      if (ln == 0) atomicAdd(&lsum[b * 2048 + row], s);
    }
}

// ---------- P @ V, divide by row sum, fp32 out; XCD-swizzled ----------

__global__ __launch_bounds__(256, 4) void k_pv(const u16* __restrict__ P,
                                               const u16* __restrict__ vtb,
                                               const float* __restrict__ lsum,
                                               float* __restrict__ out) {
  __shared__ __align__(16) u16 As[2 * 4096];
  __shared__ __align__(16) u16 Bs[2 * 4096];
  // bid%8 = batch = XCD: vtb slab (2MB) L2-resident; bn fastest -> P-slab reuse
  const int bid = blockIdx.x;
  const int b = bid & 7, t = bid >> 3;
  const int bm = (t >> 2) * 128, bn = (t & 3) * 128;
  const int tid = threadIdx.x, w = tid >> 6, l = tid & 63;
  f32x4 acc[4][4];
  gemm_core64(P  + (size_t)b * 2048 * 2048 + (size_t)bm * 2048,
              vtb + (size_t)b * 512 * 2048 + (size_t)bn * 2048,
              2048, 2048, 2048, As, Bs, acc, w, l);

  const int wm = (w & 1) << 6, wn = (w >> 1) << 6;
  const int ln = l & 15, lq = l >> 4;
#pragma unroll
  for (int mt = 0; mt < 4; mt++)
#pragma unroll
    for (int r = 0; r < 4; r++) {
      int row = bm + wm + mt * 16 + lq * 4 + r;
      float inv = 1.0f / lsum[b * 2048 + row];
#pragma unroll
      for (int nt = 0; nt < 4; nt++) {
        int col = bn + wn + nt * 16 + ln;
        __builtin_nontemporal_store(acc[mt][nt][r] * inv,
            &out[((size_t)b * 2048 + row) * 512 + col]);
      }
    }
}

// ---------- launch ----------

extern "C" void kernel_launch(void* const* d_in, const int* in_sizes, int n_in,
                              void* d_out, int out_size, void* d_ws, size_t ws_size,
                              hipStream_t stream) {
  const float* x  = (const float*)d_in[0];
  const float* Wq = (const float*)d_in[1];
  const float* bq = (const float*)d_in[2];
  const float* Wk = (const float*)d_in[3];
  const float* bk = (const float*)d_in[4];
  const float* Wv = (const float*)d_in[5];
  const float* bv = (const float*)d_in[6];
  float* out = (float*)d_out;
  char* ws = (char*)d_ws;

  u16*  qb   = (u16*)(ws + 0);            // 16,777,216
  u16*  kb   = (u16*)(ws + 16777216);     // 16,777,216
  u16*  vtb  = (u16*)(ws + 33554432);     // 16,777,216
  float* lsum = (float*)(ws + 50331648);  //     65,536
  u16*  P    = (u16*)(ws + 50397184);     // 67,108,864 (ends 117,506,048)

  k_proj<<<dim3(4, 128, 1), 256, 0, stream>>>(x, Wq, Wk, Wv, bq, bk, bv,
                                              qb, kb, vtb, lsum);
  k_qk<<<2048, 256, 0, stream>>>(qb, kb, P, lsum);
  k_pv<<<512, 256, 0, stream>>>(P, vtb, lsum, out);
}

// Round 13
// 205.456 us; speedup vs baseline: 1.0508x; 1.0063x over previous
//
#include <hip/hip_runtime.h>
#include <hip/hip_bf16.h>
#include <math.h>

typedef unsigned short u16;
using short8 = __attribute__((ext_vector_type(8))) short;
using f32x4  = __attribute__((ext_vector_type(4))) float;

#define BK 32

// ---------- helpers ----------

__device__ __forceinline__ u16 f2bf(float f) {
  union { float f; unsigned u; } v; v.f = f;
  unsigned r = v.u + 0x7FFFu + ((v.u >> 16) & 1u);   // RNE
  return (u16)(r >> 16);
}

__device__ __forceinline__ float fexp(float x) { return __expf(x); }

__device__ __forceinline__ void gld16(const void* g, void* l) {
  __builtin_amdgcn_global_load_lds(
      (const __attribute__((address_space(1))) void*)g,
      (__attribute__((address_space(3))) void*)l,
      16, 0, 0);
}

// ---------- 4-wave GEMM core (R0-proven): 16x16x32 MFMA, BK=64 ----------
// 128x128 C tile of A[*,lda] @ B[*,ldb]^T, row-major K-contiguous bf16.
// Simple 2-barrier drain loop; relies on multi-block residency for overlap.
// K-layout-agnostic (verified R6): any permutation of the K axis applied
// identically to A and B rows leaves C invariant.

__device__ __forceinline__ void gemm_core64(const u16* __restrict__ Ag,
                                            const u16* __restrict__ Bg,
                                            int K, int lda, int ldb,
                                            u16* As, u16* Bs,
                                            f32x4 acc[4][4], int w, int l) {
  const int wm = (w & 1) << 6, wn = (w >> 1) << 6;
  const int ln = l & 15, lq = l >> 4;
  const int sr0 = w * 16 + (l >> 2);
  const int sr1 = 64 + sr0;
  const int skp = (l & 3) * 8;                       // physical LDS chunk
  const int skg = ((l & 3) ^ ((l >> 3) & 3)) * 8;    // logical/global chunk
  const int kro = (lq ^ ((ln >> 1) & 3)) * 8;        // read-side phys chunk

#pragma unroll
  for (int mt = 0; mt < 4; mt++)
#pragma unroll
    for (int nt = 0; nt < 4; nt++) acc[mt][nt] = (f32x4)0.0f;

  for (int k0 = 0; k0 < K; k0 += 64) {
    __syncthreads();
    gld16(Ag + (size_t)sr0 * lda + k0 + skg, As + sr0 * BK + skp);
    gld16(Ag + (size_t)sr1 * lda + k0 + skg, As + sr1 * BK + skp);
    gld16(Ag + (size_t)sr0 * lda + k0 + 32 + skg, As + 4096 + sr0 * BK + skp);
    gld16(Ag + (size_t)sr1 * lda + k0 + 32 + skg, As + 4096 + sr1 * BK + skp);
    gld16(Bg + (size_t)sr0 * ldb + k0 + skg, Bs + sr0 * BK + skp);
    gld16(Bg + (size_t)sr1 * ldb + k0 + skg, Bs + sr1 * BK + skp);
    gld16(Bg + (size_t)sr0 * ldb + k0 + 32 + skg, Bs + 4096 + sr0 * BK + skp);
    gld16(Bg + (size_t)sr1 * ldb + k0 + 32 + skg, Bs + 4096 + sr1 * BK + skp);
    __syncthreads();
#pragma unroll
    for (int h = 0; h < 2; h++) {
      const u16* Ah = As + h * 4096;
      const u16* Bh = Bs + h * 4096;
      short8 af[4], bf[4];
#pragma unroll
      for (int mt = 0; mt < 4; mt++)
        af[mt] = *(const short8*)(Ah + (wm + mt * 16 + ln) * BK + kro);
#pragma unroll
      for (int nt = 0; nt < 4; nt++)
        bf[nt] = *(const short8*)(Bh + (wn + nt * 16 + ln) * BK + kro);
#pragma unroll
      for (int mt = 0; mt < 4; mt++)
#pragma unroll
        for (int nt = 0; nt < 4; nt++)
          acc[mt][nt] = __builtin_amdgcn_mfma_f32_16x16x32_bf16(
              af[mt], bf[nt], acc[mt][nt], 0, 0, 0);
    }
  }
}

// ---------- small conversion kernel: W transpose + bcat + lsum zero ----------
// Separate kernel (R12 lesson: in-proj W staging costs more than this
// kernel + its boundary -- async gld16 of pre-converted Wt wins).

__global__ __launch_bounds__(256) void k_conv(
    const float* __restrict__ Wq, const float* __restrict__ Wk,
    const float* __restrict__ Wv, const float* __restrict__ bq,
    const float* __restrict__ bk, const float* __restrict__ bv,
    u16* __restrict__ Wt, float* __restrict__ bcat,
    float* __restrict__ lsum) {
  const int bid = blockIdx.x;
  if (bid < 1536) {
    int i = bid * 256 + threadIdx.x;
    int nn = i >> 8, e = i & 255;
    int sel = nn >> 9, c = nn & 511;
    const float* W = (sel == 0) ? Wq : (sel == 1) ? Wk : Wv;
    Wt[i] = f2bf(W[e * 512 + c]);
    if (e == 0) {
      const float* bb = (sel == 0) ? bq : (sel == 1) ? bk : bv;
      bcat[nn] = bb[c];
    }
  } else {
    int i = (bid - 1536) * 256 + threadIdx.x;   // 64 blocks -> 16384 floats
    lsum[i] = 0.0f;
  }
}

// ---------- projection: A-resident shared-slab GEMM, fused x->bf16 ----------
// R10 structure: A slab reg-staged from fp32 x via NON-TEMPORAL loads (nt
// keeps streaming x from evicting the qb/kb lines k_qk re-reads: qk 64->56.6
// measured) + async Wt gld16 B-staging. vtb t-axis PERMUTED within each
// 64-group (matches k_qk's P columns) with R12's regrouped ushort4 scratch
// stores (fixes the R10 scalar-u16 scatter).

__global__ __launch_bounds__(256) void k_proj(
    const float* __restrict__ x, const u16* __restrict__ Wt,
    const float* __restrict__ bcat, u16* __restrict__ qb,
    u16* __restrict__ kb, u16* __restrict__ vtb) {
  __shared__ __align__(16) u16 As8[8 * 4096];  // 64 KB: 8 windows x [128][32]
  __shared__ __align__(16) u16 Bs[2 * 4096];   // 16 KB: 2 windows
  const int bm = blockIdx.y * 128;
  const int bnq = blockIdx.x;                  // 0..3: 128-col quarter of 512
  const int tid = threadIdx.x, w = tid >> 6, l = tid & 63;
  const int wm = (w & 1) << 6, wn = (w >> 1) << 6;
  const int ln = l & 15, lq = l >> 4;
  const int sr0 = w * 16 + (l >> 2);
  const int sr1 = 64 + sr0;
  const int skp = (l & 3) * 8;
  const int skg = ((l & 3) ^ ((l >> 3) & 3)) * 8;
  const int kro = (lq ^ ((ln >> 1) & 3)) * 8;

  // stage all 8 A windows once: fp32 nt-load + convert + LDS write
#pragma unroll
  for (int kw = 0; kw < 8; kw++) {
    const f32x4* s0 = (const f32x4*)(x + (size_t)(bm + sr0) * 256 + kw * 32 + skg);
    const f32x4* s1 = (const f32x4*)(x + (size_t)(bm + sr1) * 256 + kw * 32 + skg);
    f32x4 a0 = __builtin_nontemporal_load(s0);
    f32x4 a1 = __builtin_nontemporal_load(s0 + 1);
    f32x4 b0 = __builtin_nontemporal_load(s1);
    f32x4 b1 = __builtin_nontemporal_load(s1 + 1);
    short8 v0, v1;
#pragma unroll
    for (int j = 0; j < 4; j++) {
      ((u16*)&v0)[j]     = f2bf(a0[j]);
      ((u16*)&v0)[4 + j] = f2bf(a1[j]);
      ((u16*)&v1)[j]     = f2bf(b0[j]);
      ((u16*)&v1)[4 + j] = f2bf(b1[j]);
    }
    *(short8*)(As8 + kw * 4096 + sr0 * BK + skp) = v0;
    *(short8*)(As8 + kw * 4096 + sr1 * BK + skp) = v1;
  }

  const int b = bm >> 11, t0 = bm & 2047;
  const int cb = bnq * 128;

  for (int p = 0; p < 3; p++) {
    const u16* Bg = Wt + (size_t)(p * 512 + cb) * 256;
    f32x4 acc[4][4];
#pragma unroll
    for (int mt = 0; mt < 4; mt++)
#pragma unroll
      for (int nt = 0; nt < 4; nt++) acc[mt][nt] = (f32x4)0.0f;

#pragma unroll
    for (int it2 = 0; it2 < 4; it2++) {
      __syncthreads();
      gld16(Bg + (size_t)sr0 * 256 + it2 * 64 + skg, Bs + sr0 * BK + skp);
      gld16(Bg + (size_t)sr1 * 256 + it2 * 64 + skg, Bs + sr1 * BK + skp);
      gld16(Bg + (size_t)sr0 * 256 + it2 * 64 + 32 + skg,
            Bs + 4096 + sr0 * BK + skp);
      gld16(Bg + (size_t)sr1 * 256 + it2 * 64 + 32 + skg,
            Bs + 4096 + sr1 * BK + skp);
      __syncthreads();
#pragma unroll
      for (int h = 0; h < 2; h++) {
        const u16* Aw = As8 + (it2 * 2 + h) * 4096;
        const u16* Bh = Bs + h * 4096;
        short8 af[4], bf[4];
#pragma unroll
        for (int mt = 0; mt < 4; mt++)
          af[mt] = *(const short8*)(Aw + (wm + mt * 16 + ln) * BK + kro);
#pragma unroll
        for (int nt = 0; nt < 4; nt++)
          bf[nt] = *(const short8*)(Bh + (wn + nt * 16 + ln) * BK + kro);
#pragma unroll
        for (int mt = 0; mt < 4; mt++)
#pragma unroll
          for (int nt = 0; nt < 4; nt++)
            acc[mt][nt] = __builtin_amdgcn_mfma_f32_16x16x32_bf16(
                af[mt], bf[nt], acc[mt][nt], 0, 0, 0);
      }
    }

    if (p < 2) {
      // PERMUTED channel layout within each 64-col group (R6-verified):
      // memory position m = ln*4 + nt holds logical channel nt*16 + ln.
      // Applied identically to qb AND kb -> QK^T invariant.
      u16* dst = p ? kb : qb;
#pragma unroll
      for (int mt = 0; mt < 4; mt++)
#pragma unroll
        for (int r = 0; r < 4; r++) {
          int row = bm + wm + mt * 16 + lq * 4 + r;
          ushort4 o;
#pragma unroll
          for (int nt = 0; nt < 4; nt++) {
            int col = wn + nt * 16 + ln;           // logical col (bias idx)
            float v = acc[mt][nt][r] + bcat[p * 512 + cb + col];
            float ov = (p == 0) ? __builtin_amdgcn_rcpf(1.0f + fexp(-v)) : v;
            ((u16*)&o)[nt] = f2bf(ov);
          }
          *(ushort4*)&dst[(size_t)row * 512 + cb + wn + ln * 4] = o;
        }
    } else {
      // v path: transpose to vtb[b][col][t], t-axis permuted within each
      // 64-group (logical local-t mt*16+lq*4+r at position lq*16+r*4+mt).
      // Regrouped across mt -> one ushort4 LDS store per (nt,r) (R12 fix).
      u16* tr = As8;                            // reuse dead A slab
#pragma unroll
      for (int h = 0; h < 2; h++) {
        __syncthreads();
        if ((w & 1) == h) {
#pragma unroll
          for (int nt = 0; nt < 4; nt++) {
            int c = wn + nt * 16 + ln;
            float bias = bcat[1024 + cb + c];
#pragma unroll
            for (int r = 0; r < 4; r++) {
              ushort4 o;
#pragma unroll
              for (int mm = 0; mm < 4; mm++)
                ((u16*)&o)[mm] = f2bf(acc[mm][nt][r] + bias);
              *(ushort4*)&tr[c * 68 + lq * 16 + r * 4] = o;
            }
          }
        }
        __syncthreads();
        int c2 = tid >> 1, half = tid & 1;
        size_t dbase = ((size_t)b * 512 + cb + c2) * 2048 + t0 + h * 64 + half * 32;
#pragma unroll
        for (int j = 0; j < 4; j++) {
          ushort4 a0 = *(const ushort4*)&tr[c2 * 68 + half * 32 + j * 8];
          ushort4 a1 = *(const ushort4*)&tr[c2 * 68 + half * 32 + j * 8 + 4];
          *(ushort4*)&vtb[dbase + j * 8] = a0;
          *(ushort4*)&vtb[dbase + j * 8 + 4] = a1;
        }
      }
    }
  }
}

// ---------- QK^T + elu + exp -> P (bf16, permuted cols), row sums ----------

__global__ __launch_bounds__(256, 4) void k_qk(const u16* __restrict__ qb,
                                               const u16* __restrict__ kb,
                                               u16* __restrict__ P,
                                               float* __restrict__ lsum) {
  __shared__ __align__(16) u16 As[2 * 4096];   // 16 KB (BK=64, 2 windows)
  __shared__ __align__(16) u16 Bs[2 * 4096];   // 16 KB
  // bid%8 = batch = XCD round-robin: each XCD's L2 keeps its batch's q+k (4MB)
  const int bid = blockIdx.x;
  const int b = bid & 7, t = bid >> 3;
  const int bm = (t >> 4) * 128, bn = (t & 15) * 128;
  const size_t ob = (size_t)b * 2048 * 512;
  const int tid = threadIdx.x, w = tid >> 6, l = tid & 63;
  f32x4 acc[4][4];
  gemm_core64(qb + ob + (size_t)bm * 512, kb + ob + (size_t)bn * 512,
              512, 512, 512, As, Bs, acc, w, l);

  const int wm = (w & 1) << 6, wn = (w >> 1) << 6;
  const int ln = l & 15, lq = l >> 4;
  const float scale = 0.0625f;  // 1/sqrt(256)
  // P columns stored PERMUTED within each aligned 64-group: memory position
  // m = ln*4 + nt holds logical kv-col nt*16 + ln. vtb's t-axis uses the
  // same permutation -> P@V invariant. One ushort4 store per (mt,r).
#pragma unroll
  for (int mt = 0; mt < 4; mt++)
#pragma unroll
    for (int r = 0; r < 4; r++) {
      int row = bm + wm + mt * 16 + lq * 4 + r;
      float s = 0.0f;
      ushort4 o;
#pragma unroll
      for (int nt = 0; nt < 4; nt++) {
        float v = acc[mt][nt][r] * scale;
        float e = (v > 0.0f) ? v : (fexp(v) - 1.0f);   // elu (hw exp)
        float p = fexp(e);    // unnormalized softmax (elu >= -1, no max sub)
        ((u16*)&o)[nt] = f2bf(p);
        s += p;
      }
      *(ushort4*)&P[((size_t)b * 2048 + row) * 2048 + bn + wn + ln * 4] = o;
#pragma unroll
      for (int o2 = 1; o2 < 16; o2 <<= 1) s += __shfl_xor(s, o2);
      if (ln == 0) atomicAdd(&lsum[b * 2048 + row], s);
    }
}

// ---------- P @ V, divide by row sum, fp32 out; XCD-swizzled ----------

__global__ __launch_bounds__(256, 4) void k_pv(const u16* __restrict__ P,
                                               const u16* __restrict__ vtb,
                                               const float* __restrict__ lsum,
                                               float* __restrict__ out) {
  __shared__ __align__(16) u16 As[2 * 4096];
  __shared__ __align__(16) u16 Bs[2 * 4096];
  // bid%8 = batch = XCD: vtb slab (2MB) L2-resident; bn fastest -> P-slab reuse
  const int bid = blockIdx.x;
  const int b = bid & 7, t = bid >> 3;
  const int bm = (t >> 2) * 128, bn = (t & 3) * 128;
  const int tid = threadIdx.x, w = tid >> 6, l = tid & 63;
  f32x4 acc[4][4];
  gemm_core64(P  + (size_t)b * 2048 * 2048 + (size_t)bm * 2048,
              vtb + (size_t)b * 512 * 2048 + (size_t)bn * 2048,
              2048, 2048, 2048, As, Bs, acc, w, l);

  const int wm = (w & 1) << 6, wn = (w >> 1) << 6;
  const int ln = l & 15, lq = l >> 4;
#pragma unroll
  for (int mt = 0; mt < 4; mt++)
#pragma unroll
    for (int r = 0; r < 4; r++) {
      int row = bm + wm + mt * 16 + lq * 4 + r;
      float inv = 1.0f / lsum[b * 2048 + row];
#pragma unroll
      for (int nt = 0; nt < 4; nt++) {
        int col = bn + wn + nt * 16 + ln;
        out[((size_t)b * 2048 + row) * 512 + col] = acc[mt][nt][r] * inv;
      }
    }
}

// ---------- launch ----------

extern "C" void kernel_launch(void* const* d_in, const int* in_sizes, int n_in,
                              void* d_out, int out_size, void* d_ws, size_t ws_size,
                              hipStream_t stream) {
  const float* x  = (const float*)d_in[0];
  const float* Wq = (const float*)d_in[1];
  const float* bq = (const float*)d_in[2];
  const float* Wk = (const float*)d_in[3];
  const float* bk = (const float*)d_in[4];
  const float* Wv = (const float*)d_in[5];
  const float* bv = (const float*)d_in[6];
  float* out = (float*)d_out;
  char* ws = (char*)d_ws;

  u16*  qb   = (u16*)(ws + 0);            // 16,777,216
  u16*  kb   = (u16*)(ws + 16777216);     // 16,777,216
  u16*  vtb  = (u16*)(ws + 33554432);     // 16,777,216
  float* lsum = (float*)(ws + 50331648);  //     65,536
  u16*  P    = (u16*)(ws + 50397184);     // 67,108,864 (ends 117,506,048)
  u16*  Wt   = (u16*)(ws + 58785792);     //    786,432 (alias P)
  float* bcat = (float*)(ws + 59572224);  //      6,144 (alias P)

  k_conv<<<1600, 256, 0, stream>>>(Wq, Wk, Wv, bq, bk, bv, Wt, bcat, lsum);
  k_proj<<<dim3(4, 128, 1), 256, 0, stream>>>(x, Wt, bcat, qb, kb, vtb);
  k_qk<<<2048, 256, 0, stream>>>(qb, kb, P, lsum);
  k_pv<<<512, 256, 0, stream>>>(P, vtb, lsum, out);
}

// Round 14
// 195.305 us; speedup vs baseline: 1.1055x; 1.0520x over previous
//
#include <hip/hip_runtime.h>
#include <hip/hip_bf16.h>
#include <math.h>

typedef unsigned short u16;
using short8 = __attribute__((ext_vector_type(8))) short;
using f32x4  = __attribute__((ext_vector_type(4))) float;

#define BK 32

// ---------- helpers ----------

__device__ __forceinline__ u16 f2bf(float f) {
  union { float f; unsigned u; } v; v.f = f;
  unsigned r = v.u + 0x7FFFu + ((v.u >> 16) & 1u);   // RNE
  return (u16)(r >> 16);
}

__device__ __forceinline__ float fexp(float x) { return __expf(x); }

__device__ __forceinline__ void gld16(const void* g, void* l) {
  __builtin_amdgcn_global_load_lds(
      (const __attribute__((address_space(1))) void*)g,
      (__attribute__((address_space(3))) void*)l,
      16, 0, 0);
}

// ---------- 4-wave GEMM core (R0-proven): 16x16x32 MFMA, BK=64 ----------
// 128x128 C tile of A[*,lda] @ B[*,ldb]^T, row-major K-contiguous bf16.
// K-layout-agnostic (verified R6). Staging algebra: LDS row r, physical
// chunk p holds logical chunk p ^ ((r>>1)&3); read kro matches.

__device__ __forceinline__ void gemm_core64(const u16* __restrict__ Ag,
                                            const u16* __restrict__ Bg,
                                            int K, int lda, int ldb,
                                            u16* As, u16* Bs,
                                            f32x4 acc[4][4], int w, int l) {
  const int wm = (w & 1) << 6, wn = (w >> 1) << 6;
  const int ln = l & 15, lq = l >> 4;
  const int sr0 = w * 16 + (l >> 2);
  const int sr1 = 64 + sr0;
  const int skp = (l & 3) * 8;                       // physical LDS chunk
  const int skg = ((l & 3) ^ ((l >> 3) & 3)) * 8;    // logical/global chunk
  const int kro = (lq ^ ((ln >> 1) & 3)) * 8;        // read-side phys chunk

#pragma unroll
  for (int mt = 0; mt < 4; mt++)
#pragma unroll
    for (int nt = 0; nt < 4; nt++) acc[mt][nt] = (f32x4)0.0f;

  for (int k0 = 0; k0 < K; k0 += 64) {
    __syncthreads();
    gld16(Ag + (size_t)sr0 * lda + k0 + skg, As + sr0 * BK + skp);
    gld16(Ag + (size_t)sr1 * lda + k0 + skg, As + sr1 * BK + skp);
    gld16(Ag + (size_t)sr0 * lda + k0 + 32 + skg, As + 4096 + sr0 * BK + skp);
    gld16(Ag + (size_t)sr1 * lda + k0 + 32 + skg, As + 4096 + sr1 * BK + skp);
    gld16(Bg + (size_t)sr0 * ldb + k0 + skg, Bs + sr0 * BK + skp);
    gld16(Bg + (size_t)sr1 * ldb + k0 + skg, Bs + sr1 * BK + skp);
    gld16(Bg + (size_t)sr0 * ldb + k0 + 32 + skg, Bs + 4096 + sr0 * BK + skp);
    gld16(Bg + (size_t)sr1 * ldb + k0 + 32 + skg, Bs + 4096 + sr1 * BK + skp);
    __syncthreads();
#pragma unroll
    for (int h = 0; h < 2; h++) {
      const u16* Ah = As + h * 4096;
      const u16* Bh = Bs + h * 4096;
      short8 af[4], bf[4];
#pragma unroll
      for (int mt = 0; mt < 4; mt++)
        af[mt] = *(const short8*)(Ah + (wm + mt * 16 + ln) * BK + kro);
#pragma unroll
      for (int nt = 0; nt < 4; nt++)
        bf[nt] = *(const short8*)(Bh + (wn + nt * 16 + ln) * BK + kro);
#pragma unroll
      for (int mt = 0; mt < 4; mt++)
#pragma unroll
        for (int nt = 0; nt < 4; nt++)
          acc[mt][nt] = __builtin_amdgcn_mfma_f32_16x16x32_bf16(
              af[mt], bf[nt], acc[mt][nt], 0, 0, 0);
    }
  }
}

// ---------- small conversion kernel: W transpose + bcat + lsum zero ----------

__global__ __launch_bounds__(256) void k_conv(
    const float* __restrict__ Wq, const float* __restrict__ Wk,
    const float* __restrict__ Wv, const float* __restrict__ bq,
    const float* __restrict__ bk, const float* __restrict__ bv,
    u16* __restrict__ Wt, float* __restrict__ bcat,
    float* __restrict__ lsum) {
  const int bid = blockIdx.x;
  if (bid < 1536) {
    int i = bid * 256 + threadIdx.x;
    int nn = i >> 8, e = i & 255;
    int sel = nn >> 9, c = nn & 511;
    const float* W = (sel == 0) ? Wq : (sel == 1) ? Wk : Wv;
    Wt[i] = f2bf(W[e * 512 + c]);
    if (e == 0) {
      const float* bb = (sel == 0) ? bq : (sel == 1) ? bk : bv;
      bcat[nn] = bb[c];
    }
  } else {
    int i = (bid - 1536) * 256 + threadIdx.x;   // 64 blocks -> 16384 floats
    lsum[i] = 0.0f;
  }
}

// ---------- projection: A-resident shared-slab GEMM, fused x->bf16 ----------
// R13 config unchanged (single-variable round: only k_qk changes).

__global__ __launch_bounds__(256) void k_proj(
    const float* __restrict__ x, const u16* __restrict__ Wt,
    const float* __restrict__ bcat, u16* __restrict__ qb,
    u16* __restrict__ kb, u16* __restrict__ vtb) {
  __shared__ __align__(16) u16 As8[8 * 4096];  // 64 KB: 8 windows x [128][32]
  __shared__ __align__(16) u16 Bs[2 * 4096];   // 16 KB: 2 windows
  const int bm = blockIdx.y * 128;
  const int bnq = blockIdx.x;                  // 0..3: 128-col quarter of 512
  const int tid = threadIdx.x, w = tid >> 6, l = tid & 63;
  const int wm = (w & 1) << 6, wn = (w >> 1) << 6;
  const int ln = l & 15, lq = l >> 4;
  const int sr0 = w * 16 + (l >> 2);
  const int sr1 = 64 + sr0;
  const int skp = (l & 3) * 8;
  const int skg = ((l & 3) ^ ((l >> 3) & 3)) * 8;
  const int kro = (lq ^ ((ln >> 1) & 3)) * 8;

  // stage all 8 A windows once: fp32 nt-load + convert + LDS write
#pragma unroll
  for (int kw = 0; kw < 8; kw++) {
    const f32x4* s0 = (const f32x4*)(x + (size_t)(bm + sr0) * 256 + kw * 32 + skg);
    const f32x4* s1 = (const f32x4*)(x + (size_t)(bm + sr1) * 256 + kw * 32 + skg);
    f32x4 a0 = __builtin_nontemporal_load(s0);
    f32x4 a1 = __builtin_nontemporal_load(s0 + 1);
    f32x4 b0 = __builtin_nontemporal_load(s1);
    f32x4 b1 = __builtin_nontemporal_load(s1 + 1);
    short8 v0, v1;
#pragma unroll
    for (int j = 0; j < 4; j++) {
      ((u16*)&v0)[j]     = f2bf(a0[j]);
      ((u16*)&v0)[4 + j] = f2bf(a1[j]);
      ((u16*)&v1)[j]     = f2bf(b0[j]);
      ((u16*)&v1)[4 + j] = f2bf(b1[j]);
    }
    *(short8*)(As8 + kw * 4096 + sr0 * BK + skp) = v0;
    *(short8*)(As8 + kw * 4096 + sr1 * BK + skp) = v1;
  }

  const int b = bm >> 11, t0 = bm & 2047;
  const int cb = bnq * 128;

  for (int p = 0; p < 3; p++) {
    const u16* Bg = Wt + (size_t)(p * 512 + cb) * 256;
    f32x4 acc[4][4];
#pragma unroll
    for (int mt = 0; mt < 4; mt++)
#pragma unroll
      for (int nt = 0; nt < 4; nt++) acc[mt][nt] = (f32x4)0.0f;

#pragma unroll
    for (int it2 = 0; it2 < 4; it2++) {
      __syncthreads();
      gld16(Bg + (size_t)sr0 * 256 + it2 * 64 + skg, Bs + sr0 * BK + skp);
      gld16(Bg + (size_t)sr1 * 256 + it2 * 64 + skg, Bs + sr1 * BK + skp);
      gld16(Bg + (size_t)sr0 * 256 + it2 * 64 + 32 + skg,
            Bs + 4096 + sr0 * BK + skp);
      gld16(Bg + (size_t)sr1 * 256 + it2 * 64 + 32 + skg,
            Bs + 4096 + sr1 * BK + skp);
      __syncthreads();
#pragma unroll
      for (int h = 0; h < 2; h++) {
        const u16* Aw = As8 + (it2 * 2 + h) * 4096;
        const u16* Bh = Bs + h * 4096;
        short8 af[4], bf[4];
#pragma unroll
        for (int mt = 0; mt < 4; mt++)
          af[mt] = *(const short8*)(Aw + (wm + mt * 16 + ln) * BK + kro);
#pragma unroll
        for (int nt = 0; nt < 4; nt++)
          bf[nt] = *(const short8*)(Bh + (wn + nt * 16 + ln) * BK + kro);
#pragma unroll
        for (int mt = 0; mt < 4; mt++)
#pragma unroll
          for (int nt = 0; nt < 4; nt++)
            acc[mt][nt] = __builtin_amdgcn_mfma_f32_16x16x32_bf16(
                af[mt], bf[nt], acc[mt][nt], 0, 0, 0);
      }
    }

    if (p < 2) {
      // PERMUTED channel layout within each 64-col group (R6-verified).
      u16* dst = p ? kb : qb;
#pragma unroll
      for (int mt = 0; mt < 4; mt++)
#pragma unroll
        for (int r = 0; r < 4; r++) {
          int row = bm + wm + mt * 16 + lq * 4 + r;
          ushort4 o;
#pragma unroll
          for (int nt = 0; nt < 4; nt++) {
            int col = wn + nt * 16 + ln;           // logical col (bias idx)
            float v = acc[mt][nt][r] + bcat[p * 512 + cb + col];
            float ov = (p == 0) ? __builtin_amdgcn_rcpf(1.0f + fexp(-v)) : v;
            ((u16*)&o)[nt] = f2bf(ov);
          }
          *(ushort4*)&dst[(size_t)row * 512 + cb + wn + ln * 4] = o;
        }
    } else {
      // v path: transpose to vtb[b][col][t], t-axis permuted (R12 fix:
      // one ushort4 LDS store per (nt,r)).
      u16* tr = As8;                            // reuse dead A slab
#pragma unroll
      for (int h = 0; h < 2; h++) {
        __syncthreads();
        if ((w & 1) == h) {
#pragma unroll
          for (int nt = 0; nt < 4; nt++) {
            int c = wn + nt * 16 + ln;
            float bias = bcat[1024 + cb + c];
#pragma unroll
            for (int r = 0; r < 4; r++) {
              ushort4 o;
#pragma unroll
              for (int mm = 0; mm < 4; mm++)
                ((u16*)&o)[mm] = f2bf(acc[mm][nt][r] + bias);
              *(ushort4*)&tr[c * 68 + lq * 16 + r * 4] = o;
            }
          }
        }
        __syncthreads();
        int c2 = tid >> 1, half = tid & 1;
        size_t dbase = ((size_t)b * 512 + cb + c2) * 2048 + t0 + h * 64 + half * 32;
#pragma unroll
        for (int j = 0; j < 4; j++) {
          ushort4 a0 = *(const ushort4*)&tr[c2 * 68 + half * 32 + j * 8];
          ushort4 a1 = *(const ushort4*)&tr[c2 * 68 + half * 32 + j * 8 + 4];
          *(ushort4*)&vtb[dbase + j * 8] = a0;
          *(ushort4*)&vtb[dbase + j * 8 + 4] = a1;
        }
      }
    }
  }
}

// ---------- QK^T + elu + exp -> P: 256x256 tile, 8-wave, 4-phase pipeline ----
// Faithful fine-interleave port (m196/m198 structure) using the verified XOR
// window layout. BK=64 K-tiles, 2 LDS buffers (128KB). Per tile T, 4 phases:
//   gate: s_waitcnt vmcnt(4) + barrier   (kh ready; 4 newer loads in flight)
//   ph: ds_read slice | issue 2 staging windows of tile T+1 | setprio-MFMA | bar
// Staging of tile T+1 goes to buf[T&1]^1 (freed at tile T-1's last barrier).
// Counted waits: at each gate exactly 4 newer windows are legitimately in
// flight (issue order A0,B0,A1,B1 per tile) -> vmcnt(4), never a hot drain.

__global__ __launch_bounds__(512, 2) void k_qk(const u16* __restrict__ qb,
                                               const u16* __restrict__ kb,
                                               u16* __restrict__ P,
                                               float* __restrict__ lsum) {
  __shared__ __align__(16) u16 S[65536];       // 128KB: 2 bufs x (A16K+B16K) u16
  const int bid = blockIdx.x;
  const int b = bid & 7, t = bid >> 3;         // XCD = batch
  const int bm = (t >> 3) * 256, bn = (t & 7) * 256;
  const size_t ob = (size_t)b * 2048 * 512;
  const u16* Ag = qb + ob + (size_t)bm * 512;
  const u16* Bg = kb + ob + (size_t)bn * 512;
  const int tid = threadIdx.x;
  const int w = tid >> 6, l = tid & 63;
  const int wm2 = w & 1, wn2 = w >> 1;         // 2M x 4N waves; wave out 128x64
  const int ln = l & 15, lq = l >> 4;
  const int srow = tid >> 2;                   // staging row 0..127
  const int skp = (tid & 3) * 8;
  const int skg = ((tid & 3) ^ ((tid >> 3) & 3)) * 8;
  const int kro = (lq ^ ((ln >> 1) & 3)) * 8;

  f32x4 acc[8][4];
#pragma unroll
  for (int mt = 0; mt < 8; mt++)
#pragma unroll
    for (int nt = 0; nt < 4; nt++) acc[mt][nt] = (f32x4)0.0f;

  // stage one [128][32] window: op offset 0 (A) / 16384 (B)
  auto stageW = [&](const u16* G, int T, int kh, int rh, int nb, int opoff) {
    gld16(G + (size_t)(rh * 128 + srow) * 512 + T * 64 + kh * 32 + skg,
          S + nb * 32768 + opoff + (kh * 2 + rh) * 4096 + srow * 32 + skp);
  };

  // prologue: tile 0 -> buf0, order A-kh0, B-kh0, A-kh1, B-kh1
  stageW(Ag, 0, 0, 0, 0, 0);     stageW(Ag, 0, 0, 1, 0, 0);
  stageW(Bg, 0, 0, 0, 0, 16384); stageW(Bg, 0, 0, 1, 0, 16384);
  stageW(Ag, 0, 1, 0, 0, 0);     stageW(Ag, 0, 1, 1, 0, 0);
  stageW(Bg, 0, 1, 0, 0, 16384); stageW(Bg, 0, 1, 1, 0, 16384);

  for (int T = 0; T < 8; ++T) {
    const int cur = T & 1, nb = cur ^ 1;
    const u16* Ab = S + cur * 32768;
    const u16* Bb = S + cur * 32768 + 16384;
    const int aw0 = wm2 * 4096;                      // A window base, kh0
    const int brow = ((wn2 & 1) * 64 + ln) * 32;     // B row base (nt adds)
    const int bw0 = (wn2 >> 1) * 4096;               // B window base, kh0

    // gate: kh0 of tile T ready (tile T's kh1 = 4 newer loads stay in flight)
    asm volatile("s_waitcnt vmcnt(4)" ::: "memory");
    __builtin_amdgcn_s_barrier();

    short8 af[8], bf[2];
    // ---- phase 0: A kh0 (8 reads) + B nt{0,1} kh0; stage T+1 A-kh0 ----
#pragma unroll
    for (int mt = 0; mt < 8; mt++)
      af[mt] = *(const short8*)(Ab + aw0 + (mt * 16 + ln) * 32 + kro);
    bf[0] = *(const short8*)(Bb + bw0 + brow + 0 * 512 + kro);
    bf[1] = *(const short8*)(Bb + bw0 + brow + 1 * 512 + kro);
    if (T < 7) { stageW(Ag, T + 1, 0, 0, nb, 0); stageW(Ag, T + 1, 0, 1, nb, 0); }
    __builtin_amdgcn_s_setprio(1);
#pragma unroll
    for (int mt = 0; mt < 8; mt++)
#pragma unroll
      for (int j = 0; j < 2; j++)
        acc[mt][j] = __builtin_amdgcn_mfma_f32_16x16x32_bf16(
            af[mt], bf[j], acc[mt][j], 0, 0, 0);
    __builtin_amdgcn_s_setprio(0);
    __builtin_amdgcn_s_barrier();

    // ---- phase 1: B nt{2,3} kh0 (af reused); stage T+1 B-kh0 ----
    bf[0] = *(const short8*)(Bb + bw0 + brow + 2 * 512 + kro);
    bf[1] = *(const short8*)(Bb + bw0 + brow + 3 * 512 + kro);
    if (T < 7) { stageW(Bg, T + 1, 0, 0, nb, 16384); stageW(Bg, T + 1, 0, 1, nb, 16384); }
    __builtin_amdgcn_s_setprio(1);
#pragma unroll
    for (int mt = 0; mt < 8; mt++)
#pragma unroll
      for (int j = 0; j < 2; j++)
        acc[mt][2 + j] = __builtin_amdgcn_mfma_f32_16x16x32_bf16(
            af[mt], bf[j], acc[mt][2 + j], 0, 0, 0);
    __builtin_amdgcn_s_setprio(0);
    __builtin_amdgcn_s_barrier();

    // gate: kh1 of tile T ready (T+1's kh0 = 4 newer loads in flight)
    if (T < 7) {
      asm volatile("s_waitcnt vmcnt(4)" ::: "memory");
    } else {
      asm volatile("s_waitcnt vmcnt(0)" ::: "memory");
    }
    __builtin_amdgcn_s_barrier();

    // ---- phase 2: A kh1 + B nt{0,1} kh1; stage T+1 A-kh1 ----
#pragma unroll
    for (int mt = 0; mt < 8; mt++)
      af[mt] = *(const short8*)(Ab + 8192 + aw0 + (mt * 16 + ln) * 32 + kro);
    bf[0] = *(const short8*)(Bb + 8192 + bw0 + brow + 0 * 512 + kro);
    bf[1] = *(const short8*)(Bb + 8192 + bw0 + brow + 1 * 512 + kro);
    if (T < 7) { stageW(Ag, T + 1, 1, 0, nb, 0); stageW(Ag, T + 1, 1, 1, nb, 0); }
    __builtin_amdgcn_s_setprio(1);
#pragma unroll
    for (int mt = 0; mt < 8; mt++)
#pragma unroll
      for (int j = 0; j < 2; j++)
        acc[mt][j] = __builtin_amdgcn_mfma_f32_16x16x32_bf16(
            af[mt], bf[j], acc[mt][j], 0, 0, 0);
    __builtin_amdgcn_s_setprio(0);
    __builtin_amdgcn_s_barrier();

    // ---- phase 3: B nt{2,3} kh1; stage T+1 B-kh1 ----
    bf[0] = *(const short8*)(Bb + 8192 + bw0 + brow + 2 * 512 + kro);
    bf[1] = *(const short8*)(Bb + 8192 + bw0 + brow + 3 * 512 + kro);
    if (T < 7) { stageW(Bg, T + 1, 1, 0, nb, 16384); stageW(Bg, T + 1, 1, 1, nb, 16384); }
    __builtin_amdgcn_s_setprio(1);
#pragma unroll
    for (int mt = 0; mt < 8; mt++)
#pragma unroll
      for (int j = 0; j < 2; j++)
        acc[mt][2 + j] = __builtin_amdgcn_mfma_f32_16x16x32_bf16(
            af[mt], bf[j], acc[mt][2 + j], 0, 0, 0);
    __builtin_amdgcn_s_setprio(0);
    __builtin_amdgcn_s_barrier();
  }

  const float scale = 0.0625f;  // 1/sqrt(256)
  // P columns PERMUTED within each aligned 64-group (matches vtb t-axis).
#pragma unroll
  for (int mt = 0; mt < 8; mt++)
#pragma unroll
    for (int r = 0; r < 4; r++) {
      int row = bm + wm2 * 128 + mt * 16 + lq * 4 + r;
      float s = 0.0f;
      ushort4 o;
#pragma unroll
      for (int nt = 0; nt < 4; nt++) {
        float v = acc[mt][nt][r] * scale;
        float e = (v > 0.0f) ? v : (fexp(v) - 1.0f);   // elu (hw exp)
        float p = fexp(e);    // unnormalized softmax (elu >= -1, no max sub)
        ((u16*)&o)[nt] = f2bf(p);
        s += p;
      }
      *(ushort4*)&P[((size_t)b * 2048 + row) * 2048 + bn + wn2 * 64 + ln * 4] = o;
#pragma unroll
      for (int o2 = 1; o2 < 16; o2 <<= 1) s += __shfl_xor(s, o2);
      if (ln == 0) atomicAdd(&lsum[b * 2048 + row], s);
    }
}

// ---------- P @ V, divide by row sum, fp32 out; XCD-swizzled ----------

__global__ __launch_bounds__(256, 4) void k_pv(const u16* __restrict__ P,
                                               const u16* __restrict__ vtb,
                                               const float* __restrict__ lsum,
                                               float* __restrict__ out) {
  __shared__ __align__(16) u16 As[2 * 4096];
  __shared__ __align__(16) u16 Bs[2 * 4096];
  // bid%8 = batch = XCD: vtb slab (2MB) L2-resident; bn fastest -> P-slab reuse
  const int bid = blockIdx.x;
  const int b = bid & 7, t = bid >> 3;
  const int bm = (t >> 2) * 128, bn = (t & 3) * 128;
  const int tid = threadIdx.x, w = tid >> 6, l = tid & 63;
  f32x4 acc[4][4];
  gemm_core64(P  + (size_t)b * 2048 * 2048 + (size_t)bm * 2048,
              vtb + (size_t)b * 512 * 2048 + (size_t)bn * 2048,
              2048, 2048, 2048, As, Bs, acc, w, l);

  const int wm = (w & 1) << 6, wn = (w >> 1) << 6;
  const int ln = l & 15, lq = l >> 4;
#pragma unroll
  for (int mt = 0; mt < 4; mt++)
#pragma unroll
    for (int r = 0; r < 4; r++) {
      int row = bm + wm + mt * 16 + lq * 4 + r;
      float inv = 1.0f / lsum[b * 2048 + row];
#pragma unroll
      for (int nt = 0; nt < 4; nt++) {
        int col = bn + wn + nt * 16 + ln;
        out[((size_t)b * 2048 + row) * 512 + col] = acc[mt][nt][r] * inv;
      }
    }
}

// ---------- launch ----------

extern "C" void kernel_launch(void* const* d_in, const int* in_sizes, int n_in,
                              void* d_out, int out_size, void* d_ws, size_t ws_size,
                              hipStream_t stream) {
  const float* x  = (const float*)d_in[0];
  const float* Wq = (const float*)d_in[1];
  const float* bq = (const float*)d_in[2];
  const float* Wk = (const float*)d_in[3];
  const float* bk = (const float*)d_in[4];
  const float* Wv = (const float*)d_in[5];
  const float* bv = (const float*)d_in[6];
  float* out = (float*)d_out;
  char* ws = (char*)d_ws;

  u16*  qb   = (u16*)(ws + 0);            // 16,777,216
  u16*  kb   = (u16*)(ws + 16777216);     // 16,777,216
  u16*  vtb  = (u16*)(ws + 33554432);     // 16,777,216
  float* lsum = (float*)(ws + 50331648);  //     65,536
  u16*  P    = (u16*)(ws + 50397184);     // 67,108,864 (ends 117,506,048)
  u16*  Wt   = (u16*)(ws + 58785792);     //    786,432 (alias P)
  float* bcat = (float*)(ws + 59572224);  //      6,144 (alias P)

  k_conv<<<1600, 256, 0, stream>>>(Wq, Wk, Wv, bq, bk, bv, Wt, bcat, lsum);
  k_proj<<<dim3(4, 128, 1), 256, 0, stream>>>(x, Wt, bcat, qb, kb, vtb);
  k_qk<<<512, 512, 0, stream>>>(qb, kb, P, lsum);
  k_pv<<<512, 256, 0, stream>>>(P, vtb, lsum, out);
}